// Round 4
// baseline (293.944 us; speedup 1.0000x reference)
//
#include <hip/hip_runtime.h>

// Multires hash-grid encode (2D, instant-NGP style). Round 4: fully fused.
// One thread per point, all 16 levels, register accumulators, direct output.
//  - XCD-staggered hashed-level walk: block on XCD k (blockIdx%8) processes
//    hashed levels in order 6+((k+j)%10), j=0..9. All 2048 blocks are
//    near-co-resident, so each XCD's instantaneous gather footprint is ~one
//    4.19 MB table -> L2-resident (round-3 locality) without the 95 us
//    transpose pass or the 128 MiB ws round-trip.
//  - Step-ordered accumulators h[j] (compile-time register indices); final
//    un-rotation via wave-uniform switch(xcd) with constant indices.
//  - 32-bit hash math: h = ix ^ (iy*PS1) has hi=prod>>32 (<2^13, XOR with
//    ix<2^20 only touches lo). h % E = (hi*(2^32%E) + lo%E) % E with
//    2^32 % 524309 = 352277; two 32-bit magic-mul urems instead of 64-bit.
//  - ix1=ix0+1, iy1=iy0+1: exact (fy<2^20 so fy+1.0f is exact in fp32 and
//    trunc commutes) — matches reference trunc(fx+corner) bit-for-bit.
// Index semantics otherwise identical to the jax reference (validated R1-R3).

static constexpr int kPoints = 524288;

__global__ __launch_bounds__(256) void hashgrid_fused(
    const float2* __restrict__ x,
    const float2* __restrict__ tbl,
    float4* __restrict__ out)
{
    const int n   = blockIdx.x * 256 + threadIdx.x;
    const int xcd = blockIdx.x & 7;
    const float2 p = x[n];

    // ---- hashed levels 6..15, rotated start per XCD ----
    float2 h[10];
#pragma unroll
    for (int j = 0; j < 10; ++j) {
        const int   lvl6    = (xcd + j) % 10;        // wave-uniform
        const int   scale_i = 1024 << lvl6;          // 16 << (6+lvl6)
        const float scale_f = (float)scale_i;
        const unsigned base = 351462u + (unsigned)lvl6 * 524309u;

        const float fx = p.x * scale_f;
        const float fy = p.y * scale_f;
        const unsigned ix0 = (unsigned)(int)fx;
        const unsigned iy0 = (unsigned)(int)fy;
        const unsigned ix1 = ix0 + 1u;

        const float ox = fx - (float)(int)ix0;
        const float oy = fy - (float)(int)iy0;
        const float wx1 = fminf(fmaxf(ox, 0.0f), 1.0f);
        const float wx0 = fminf(fmaxf(1.0f - ox, 0.0f), 1.0f);
        const float wy1 = fminf(fmaxf(oy, 0.0f), 1.0f);
        const float wy0 = fminf(fmaxf(1.0f - oy, 0.0f), 1.0f);

        const unsigned long long prod0 = (unsigned long long)iy0 * 19349663ull;
        const unsigned long long prod1 = prod0 + 19349663ull;
        const unsigned hi0 = (unsigned)(prod0 >> 32);
        const unsigned lo0 = (unsigned)prod0;
        const unsigned hi1 = (unsigned)(prod1 >> 32);
        const unsigned lo1 = (unsigned)prod1;

        const unsigned i00 = (hi0 * 352277u + (lo0 ^ ix0) % 524309u) % 524309u;
        const unsigned i01 = (hi1 * 352277u + (lo1 ^ ix0) % 524309u) % 524309u;
        const unsigned i10 = (hi0 * 352277u + (lo0 ^ ix1) % 524309u) % 524309u;
        const unsigned i11 = (hi1 * 352277u + (lo1 ^ ix1) % 524309u) % 524309u;

        const float2 v00 = tbl[base + i00];
        const float2 v01 = tbl[base + i01];
        const float2 v10 = tbl[base + i10];
        const float2 v11 = tbl[base + i11];

        const float w00 = wx0 * wy0, w01 = wx0 * wy1;
        const float w10 = wx1 * wy0, w11 = wx1 * wy1;

        h[j].x = w00 * v00.x + w01 * v01.x + w10 * v10.x + w11 * v11.x;
        h[j].y = w00 * v00.y + w01 * v01.y + w10 * v10.y + w11 * v11.y;
    }

    // ---- dense levels 0..5 (compile-time) ----
    constexpr unsigned dbase[6] = {0u, 289u, 1378u, 5603u, 22244u, 88293u};
    float2 d[6];
#pragma unroll
    for (int l = 0; l < 6; ++l) {
        const int   scale_i = 16 << l;
        const float scale_f = (float)scale_i;
        const float fx = p.x * scale_f;
        const float fy = p.y * scale_f;
        const unsigned ix0 = (unsigned)(int)fx;
        const unsigned iy0 = (unsigned)(int)fy;

        const float ox = fx - (float)(int)ix0;
        const float oy = fy - (float)(int)iy0;
        const float wx1 = fminf(fmaxf(ox, 0.0f), 1.0f);
        const float wx0 = fminf(fmaxf(1.0f - ox, 0.0f), 1.0f);
        const float wy1 = fminf(fmaxf(oy, 0.0f), 1.0f);
        const float wy0 = fminf(fmaxf(1.0f - oy, 0.0f), 1.0f);

        const unsigned stride = (unsigned)(scale_i + 1);
        const unsigned i00 = ix0 * stride + iy0;

        const float2 v00 = tbl[dbase[l] + i00];
        const float2 v01 = tbl[dbase[l] + i00 + 1u];
        const float2 v10 = tbl[dbase[l] + i00 + stride];
        const float2 v11 = tbl[dbase[l] + i00 + stride + 1u];

        const float w00 = wx0 * wy0, w01 = wx0 * wy1;
        const float w10 = wx1 * wy0, w11 = wx1 * wy1;

        d[l].x = w00 * v00.x + w01 * v01.x + w10 * v10.x + w11 * v11.x;
        d[l].y = w00 * v00.y + w01 * v01.y + w10 * v10.y + w11 * v11.y;
    }

    // ---- un-rotate h[j] -> lvl[(xcd+j)%10] (wave-uniform switch) ----
    float2 lvl[10];
    switch (xcd) {
#define PERM_CASE(K) \
    case K: { \
        _Pragma("unroll") \
        for (int j = 0; j < 10; ++j) lvl[(K + j) % 10] = h[j]; \
    } break;
    PERM_CASE(0) PERM_CASE(1) PERM_CASE(2) PERM_CASE(3)
    PERM_CASE(4) PERM_CASE(5) PERM_CASE(6) PERM_CASE(7)
#undef PERM_CASE
    }

    // ---- write out[n][32] as 8 float4 ----
    float4* o = out + (size_t)n * 8;
    o[0] = make_float4(d[0].x, d[0].y, d[1].x, d[1].y);
    o[1] = make_float4(d[2].x, d[2].y, d[3].x, d[3].y);
    o[2] = make_float4(d[4].x, d[4].y, d[5].x, d[5].y);
    o[3] = make_float4(lvl[0].x, lvl[0].y, lvl[1].x, lvl[1].y);
    o[4] = make_float4(lvl[2].x, lvl[2].y, lvl[3].x, lvl[3].y);
    o[5] = make_float4(lvl[4].x, lvl[4].y, lvl[5].x, lvl[5].y);
    o[6] = make_float4(lvl[6].x, lvl[6].y, lvl[7].x, lvl[7].y);
    o[7] = make_float4(lvl[8].x, lvl[8].y, lvl[9].x, lvl[9].y);
}

extern "C" void kernel_launch(void* const* d_in, const int* in_sizes, int n_in,
                              void* d_out, int out_size, void* d_ws, size_t ws_size,
                              hipStream_t stream) {
    const float2* x   = (const float2*)d_in[0];
    const float2* tbl = (const float2*)d_in[1];
    hashgrid_fused<<<kPoints / 256, 256, 0, stream>>>(x, tbl, (float4*)d_out);
}

// Round 5
// 233.403 us; speedup vs baseline: 1.2594x; 1.2594x over previous
//
#include <hip/hip_runtime.h>

// Multires hash-grid encode (2D, instant-NGP style). Round 5.
// Two-pass (round-3 structure — in-kernel level rotation proved useless in R4
// because waves drift; only dispatch-order level-majoring holds locality).
// Pass 1 (level_pass4): 4 points/thread -> 16 independent gathers in flight
//   per wave (R2/R3 had 4; pass was latency-bound at 2.5 cy/line vs ~1 floor).
//   XCD-partitioned levels kept (blockIdx%8 -> XCD round-robin heuristic):
//   each XCD owns one hashed table -> gathers are L2 hits. ws stores are
//   nontemporal so the 64 MB ws stream doesn't evict the tables from L2.
// Pass 2 (transpose_out): LDS-tiled transpose ws[16][N] -> out[N][32],
//   nontemporal on both sides (no reuse). ~19 us measured in R3.
// Index math bit-exact vs the jax reference (validated R1-R4):
//   fx = x*scale fp32; corners trunc_i64(fx)+{0,1} (exact since fx < 2^20);
//   dense: ix*(scale+1)+iy; hashed: (ix ^ (iy*19349663)) % 524309 via 32-bit
//   decomposition (2^32 % 524309 = 352277), verified bit-exact in R4.

static constexpr int kPoints = 524288;
static constexpr int kLevels = 16;

__constant__ unsigned c_level_off[kLevels] = {
    0u, 289u, 1378u, 5603u, 22244u, 88293u, 351462u,
    875771u, 1400080u, 1924389u, 2448698u, 2973007u,
    3497316u, 4021625u, 4545934u, 5070243u
};

typedef unsigned int v4u __attribute__((ext_vector_type(4)));

__device__ __forceinline__ void nt_store_f2(float2* p, float2 v) {
    union { float2 f; unsigned long long u; } c; c.f = v;
    __builtin_nontemporal_store(c.u, (unsigned long long*)p);
}
__device__ __forceinline__ float2 nt_load_f2(const float2* p) {
    union { float2 f; unsigned long long u; } c;
    c.u = __builtin_nontemporal_load((const unsigned long long*)p);
    return c.f;
}
__device__ __forceinline__ void nt_store_f4(float4* p, float4 v) {
    union { float4 f; v4u u; } c; c.f = v;
    __builtin_nontemporal_store(c.u, (v4u*)p);
}

// ---- Pass 1: level-major, XCD-partitioned, 4 points per thread ----------
__global__ __launch_bounds__(256) void level_pass4(
    const float2* __restrict__ x,
    const float2* __restrict__ tbl,
    float2* __restrict__ ws)
{
    const int b    = blockIdx.x;
    const int xcd  = b & 7;
    const int slot = b >> 3;            // 0..1023 per XCD

    int level, pblk;                    // pblk: 1024-point block, 0..511
    if (slot < 512) {
        level = 6 + xcd;                // hashed levels 6..13: one per XCD
        pblk  = slot;
    } else if (slot < 576) {
        level = 14;  pblk = xcd * 64 + (slot - 512);
    } else if (slot < 640) {
        level = 15;  pblk = xcd * 64 + (slot - 576);
    } else {
        const int d = xcd * 384 + (slot - 640);   // 0..3071
        level = d >> 9;                 // dense levels 0..5
        pblk  = d & 511;
    }

    const int t  = threadIdx.x;
    const int n0 = (pblk << 10) | t;

    const int   scale_i = 16 << level;
    const float scale_f = (float)scale_i;
    const unsigned base = c_level_off[level];

    float wx0[4], wx1[4], wy0[4], wy1[4];
    unsigned idx[4][4];

#pragma unroll
    for (int k = 0; k < 4; ++k) {
        const float2 p = x[n0 + (k << 8)];
        const float fx = p.x * scale_f;
        const float fy = p.y * scale_f;
        const unsigned ix0 = (unsigned)(int)fx;
        const unsigned iy0 = (unsigned)(int)fy;
        const unsigned ix1 = ix0 + 1u;

        const float ox = fx - (float)(int)ix0;
        const float oy = fy - (float)(int)iy0;
        wx1[k] = fminf(fmaxf(ox, 0.0f), 1.0f);
        wx0[k] = fminf(fmaxf(1.0f - ox, 0.0f), 1.0f);
        wy1[k] = fminf(fmaxf(oy, 0.0f), 1.0f);
        wy0[k] = fminf(fmaxf(1.0f - oy, 0.0f), 1.0f);

        if (level < 6) {
            const unsigned stride = (unsigned)(scale_i + 1);
            const unsigned i00 = ix0 * stride + iy0;
            idx[k][0] = i00;
            idx[k][1] = i00 + 1u;
            idx[k][2] = i00 + stride;
            idx[k][3] = i00 + stride + 1u;
        } else {
            const unsigned long long prod0 = (unsigned long long)iy0 * 19349663ull;
            const unsigned long long prod1 = prod0 + 19349663ull;
            const unsigned hi0 = (unsigned)(prod0 >> 32);
            const unsigned lo0 = (unsigned)prod0;
            const unsigned hi1 = (unsigned)(prod1 >> 32);
            const unsigned lo1 = (unsigned)prod1;
            idx[k][0] = (hi0 * 352277u + (lo0 ^ ix0) % 524309u) % 524309u;
            idx[k][1] = (hi1 * 352277u + (lo1 ^ ix0) % 524309u) % 524309u;
            idx[k][2] = (hi0 * 352277u + (lo0 ^ ix1) % 524309u) % 524309u;
            idx[k][3] = (hi1 * 352277u + (lo1 ^ ix1) % 524309u) % 524309u;
        }
    }

    // 16 independent gathers in flight
    float2 v[4][4];
#pragma unroll
    for (int k = 0; k < 4; ++k)
#pragma unroll
        for (int c = 0; c < 4; ++c)
            v[k][c] = tbl[base + idx[k][c]];

#pragma unroll
    for (int k = 0; k < 4; ++k) {
        const float w00 = wx0[k] * wy0[k], w01 = wx0[k] * wy1[k];
        const float w10 = wx1[k] * wy0[k], w11 = wx1[k] * wy1[k];
        float2 r;
        r.x = w00 * v[k][0].x + w01 * v[k][1].x + w10 * v[k][2].x + w11 * v[k][3].x;
        r.y = w00 * v[k][0].y + w01 * v[k][1].y + w10 * v[k][2].y + w11 * v[k][3].y;
        nt_store_f2(&ws[(size_t)level * kPoints + n0 + (k << 8)], r);
    }
}

// ---- Pass 2: LDS-tiled transpose ws[16][N] -> out[N][8] float4 ----------
static constexpr int kTStride = 257;

__global__ __launch_bounds__(256) void transpose_out(
    const float2* __restrict__ ws,
    float4* __restrict__ out)
{
    __shared__ float2 lds[kLevels * kTStride];

    const int t  = threadIdx.x;
    const int n0 = blockIdx.x * 256;

#pragma unroll
    for (int l = 0; l < kLevels; ++l)
        lds[l * kTStride + t] = nt_load_f2(&ws[(size_t)l * kPoints + n0 + t]);

    __syncthreads();

    float4* o = out + (size_t)n0 * 8;
#pragma unroll
    for (int k = 0; k < 8; ++k) {
        const int f  = k * 256 + t;
        const int nl = f >> 3;
        const int i  = t & 7;
        const float2 a = lds[(2 * i)     * kTStride + nl];
        const float2 b = lds[(2 * i + 1) * kTStride + nl];
        nt_store_f4(&o[f], make_float4(a.x, a.y, b.x, b.y));
    }
}

// ---- Fallback: single-pass (if ws too small) ----------------------------
__global__ __launch_bounds__(256) void hashgrid_fwd(
    const float2* __restrict__ x,
    const float2* __restrict__ tbl,
    float4* __restrict__ out)
{
    const int n = blockIdx.x * blockDim.x + threadIdx.x;
    if (n >= kPoints) return;
    const float2 p = x[n];
    float acc[2 * kLevels];
#pragma unroll
    for (int l = 0; l < kLevels; ++l) {
        const int   scale_i = 16 << l;
        const float scale_f = (float)scale_i;
        const float fx = p.x * scale_f;
        const float fy = p.y * scale_f;
        const unsigned ix0 = (unsigned)(int)fx;
        const unsigned iy0 = (unsigned)(int)fy;
        const unsigned ix1 = ix0 + 1u;
        const float ox = fx - (float)(int)ix0;
        const float oy = fy - (float)(int)iy0;
        const float wx1 = fminf(fmaxf(ox, 0.0f), 1.0f);
        const float wx0 = fminf(fmaxf(1.0f - ox, 0.0f), 1.0f);
        const float wy1 = fminf(fmaxf(oy, 0.0f), 1.0f);
        const float wy0 = fminf(fmaxf(1.0f - oy, 0.0f), 1.0f);
        unsigned i00, i01, i10, i11;
        if (l < 6) {
            const unsigned stride = (unsigned)(scale_i + 1);
            i00 = ix0 * stride + iy0; i01 = i00 + 1u;
            i10 = i00 + stride;       i11 = i10 + 1u;
        } else {
            const unsigned long long prod0 = (unsigned long long)iy0 * 19349663ull;
            const unsigned long long prod1 = prod0 + 19349663ull;
            const unsigned hi0 = (unsigned)(prod0 >> 32), lo0 = (unsigned)prod0;
            const unsigned hi1 = (unsigned)(prod1 >> 32), lo1 = (unsigned)prod1;
            i00 = (hi0 * 352277u + (lo0 ^ ix0) % 524309u) % 524309u;
            i01 = (hi1 * 352277u + (lo1 ^ ix0) % 524309u) % 524309u;
            i10 = (hi0 * 352277u + (lo0 ^ ix1) % 524309u) % 524309u;
            i11 = (hi1 * 352277u + (lo1 ^ ix1) % 524309u) % 524309u;
        }
        const unsigned base = c_level_off[l];
        const float2 v00 = tbl[base + i00];
        const float2 v01 = tbl[base + i01];
        const float2 v10 = tbl[base + i10];
        const float2 v11 = tbl[base + i11];
        const float w00 = wx0 * wy0, w01 = wx0 * wy1;
        const float w10 = wx1 * wy0, w11 = wx1 * wy1;
        acc[2 * l + 0] = w00 * v00.x + w01 * v01.x + w10 * v10.x + w11 * v11.x;
        acc[2 * l + 1] = w00 * v00.y + w01 * v01.y + w10 * v10.y + w11 * v11.y;
    }
    float4* o = out + (size_t)n * 8;
#pragma unroll
    for (int i = 0; i < 8; ++i)
        o[i] = make_float4(acc[4 * i + 0], acc[4 * i + 1],
                           acc[4 * i + 2], acc[4 * i + 3]);
}

extern "C" void kernel_launch(void* const* d_in, const int* in_sizes, int n_in,
                              void* d_out, int out_size, void* d_ws, size_t ws_size,
                              hipStream_t stream) {
    const float2* x   = (const float2*)d_in[0];
    const float2* tbl = (const float2*)d_in[1];

    const size_t ws_needed = (size_t)kLevels * kPoints * sizeof(float2); // 64 MiB
    if (ws_size >= ws_needed) {
        float2* ws = (float2*)d_ws;
        level_pass4<<<kLevels * (kPoints / 1024), 256, 0, stream>>>(x, tbl, ws);
        transpose_out<<<kPoints / 256, 256, 0, stream>>>(ws, (float4*)d_out);
    } else {
        hashgrid_fwd<<<kPoints / 256, 256, 0, stream>>>(x, tbl, (float4*)d_out);
    }
}